// Round 5
// baseline (78.672 us; speedup 1.0000x reference)
//
#include <hip/hip_runtime.h>

#define LOG2E 1.4426950408889634f

typedef __attribute__((ext_vector_type(4))) float f32x4;
typedef __attribute__((ext_vector_type(4))) short s16x4;
typedef __attribute__((ext_vector_type(8))) short s16x8;
typedef __attribute__((ext_vector_type(4))) __bf16 bf16x4;
typedef __attribute__((ext_vector_type(8))) __bf16 bf16x8;

// B=2 S=2048 H=16 D=64, fp32 in/out.
#define SS 2048
#define HH 16
#define DD 64
#define HSZ (HH * DD)
#define BHSZ (SS * DD)  // 131072 elems per (b,h) plane

// ---- prep 1: K [B,S,H,D] f32 -> Kf fragment-major bf16 -------------------
// Kf[bh][subtile s][c][lane][j]: lane l -> K[key=s*16+(l&15)][d=c*32+(l>>4)*8+j]
__global__ __launch_bounds__(256) void prep_k2(const float* __restrict__ Kg,
                                               short* __restrict__ Kf) {
  const int idx = blockIdx.x * 256 + threadIdx.x;  // 524,288 chunks
  const int l  = idx & 63;
  const int c  = (idx >> 6) & 1;
  const int s  = (idx >> 7) & 127;
  const int bh = idx >> 14;
  const int b = bh >> 4, h = bh & 15;
  const int key = (s << 4) + (l & 15);
  const int d0  = (c << 5) + ((l >> 4) << 3);
  const float* src = Kg + (((size_t)b * SS + key) * HH + h) * DD + d0;
  f32x4 a = *(const f32x4*)(src);
  f32x4 b2 = *(const f32x4*)(src + 4);
  bf16x8 o;
#pragma unroll
  for (int j = 0; j < 4; ++j) {
    o[j] = (__bf16)a[j];
    o[4 + j] = (__bf16)b2[j];
  }
  *(s16x8*)(Kf + (size_t)idx * 8) = __builtin_bit_cast(s16x8, o);
}

// ---- prep 2: V [B,S,H,D] f32 -> Vf fragment-major bf16 -------------------
// Vf[bh][subtile s][nb][lane][j]: lane l -> V[key=s*16+(l>>4)*4+j][d=nb*16+(l&15)]
__global__ __launch_bounds__(256) void prep_v2(const float* __restrict__ Vg,
                                               short* __restrict__ Vf) {
  const int idx = blockIdx.x * 256 + threadIdx.x;  // 1,048,576 chunks
  const int l  = idx & 63;
  const int nb = (idx >> 6) & 3;
  const int s  = (idx >> 8) & 127;
  const int bh = idx >> 15;
  const int b = bh >> 4, h = bh & 15;
  const int d    = (nb << 4) + (l & 15);
  const int key0 = (s << 4) + ((l >> 4) << 2);
  const float* src = Vg + (((size_t)b * SS + key0) * HH + h) * DD + d;
  bf16x4 o;
#pragma unroll
  for (int j = 0; j < 4; ++j) o[j] = (__bf16)src[(size_t)j * HSZ];
  *(s16x4*)(Vf + (size_t)idx * 4) = __builtin_bit_cast(s16x4, o);
}

// ---- main: flash attention, 2-way split-K, fragment-major K/V ------------
// 512-thread block = 8 waves = 4 q-tiles x 2 key-halves. Each wave computes
// a partial (m, lsum, oacc) over its key range; half B also owns the masked
// diagonal subtile (so hot loops have NO mask check). Partials merged via
// LDS with a log-sum-exp merge; half A normalizes and stores.
// All loads are base + lane*16B/8B (coalesced, fragment-major ws layout).
// Vote-deferred softmax (THR=8 in log2 -> P <= 256); lsum lane-local,
// reduced across g only in the epilogue.

#define SUBTILE(sub, MASKED)                                                 \
  {                                                                          \
    const short* ka = kb2 + ((size_t)(sub) << 10);                           \
    f32x4 stv = {0, 0, 0, 0};                                                \
    stv = __builtin_amdgcn_mfma_f32_16x16x32_bf16(                           \
        *(const s16x8*)(ka), qf[0], stv, 0, 0, 0);                           \
    stv = __builtin_amdgcn_mfma_f32_16x16x32_bf16(                           \
        *(const s16x8*)(ka + 512), qf[1], stv, 0, 0, 0);                     \
    if (MASKED) {                                                            \
      _Pragma("unroll") for (int r = 0; r < 4; ++r)                          \
          if (g * 4 + r > lm) stv[r] = -1e30f;                               \
    }                                                                        \
    float tmax = fmaxf(fmaxf(stv[0], stv[1]), fmaxf(stv[2], stv[3]));        \
    if (!__all(tmax <= m + 8.0f)) {                                          \
      float tm = fmaxf(tmax, __shfl_xor(tmax, 16));                          \
      tm = fmaxf(tm, __shfl_xor(tm, 32));                                    \
      const float mnew = fmaxf(m, tm);                                       \
      const float fsc = exp2f(m - mnew);                                     \
      _Pragma("unroll") for (int nb = 0; nb < 4; ++nb)                       \
          _Pragma("unroll") for (int r = 0; r < 4; ++r) oacc[nb][r] *= fsc;  \
      lsum *= fsc;                                                           \
      m = mnew;                                                              \
    }                                                                        \
    f32x4 p;                                                                 \
    _Pragma("unroll") for (int r = 0; r < 4; ++r) p[r] = exp2f(stv[r] - m);  \
    lsum += (p[0] + p[1]) + (p[2] + p[3]);                                   \
    bf16x4 pb;                                                               \
    _Pragma("unroll") for (int r = 0; r < 4; ++r) pb[r] = (__bf16)p[r];      \
    const s16x4 pf = __builtin_bit_cast(s16x4, pb);                          \
    const short* vpp = vb2 + ((size_t)(sub) << 10);                          \
    oacc[0] = __builtin_amdgcn_mfma_f32_16x16x16bf16_1k(                     \
        *(const s16x4*)(vpp), pf, oacc[0], 0, 0, 0);                         \
    oacc[1] = __builtin_amdgcn_mfma_f32_16x16x16bf16_1k(                     \
        *(const s16x4*)(vpp + 256), pf, oacc[1], 0, 0, 0);                   \
    oacc[2] = __builtin_amdgcn_mfma_f32_16x16x16bf16_1k(                     \
        *(const s16x4*)(vpp + 512), pf, oacc[2], 0, 0, 0);                   \
    oacc[3] = __builtin_amdgcn_mfma_f32_16x16x16bf16_1k(                     \
        *(const s16x4*)(vpp + 768), pf, oacc[3], 0, 0, 0);                   \
  }

__global__ __launch_bounds__(512, 8) void attn_fwd5(
    const float* __restrict__ Qg, const short* __restrict__ Kf,
    const short* __restrict__ Vf, float* __restrict__ Og)
{
  __shared__ float lo[4][16][64];   // half-B oacc  [qtile][reg][lane]
  __shared__ float lml[4][2][64];   // half-B m, lsum

  const int tid  = threadIdx.x;
  const int lane = tid & 63;
  const int lm   = lane & 15;
  const int g    = lane >> 4;
  const int w    = tid >> 6;    // 0..7
  const int qw   = w >> 1;      // q-tile slot in block (0..3)
  const int half = w & 1;       // 0 = low keys (+merge), 1 = high keys (+diag)

  const int bh = blockIdx.x;  // 0..31
  const int t  = ((gridDim.y - 1 - blockIdx.y) << 2) | qw;  // heavy-first
  const int qb = t << 4;
  const int n  = t + 1;       // subtile count for this q-tile

  const size_t qbase = (size_t)(bh >> 4) * SS * HSZ + (size_t)(bh & 15) * DD;
  const short* kb2 = Kf + (size_t)bh * BHSZ + lane * 8;
  const short* vb2 = Vf + (size_t)bh * BHSZ + lane * 4;

  // Q frag (B operand of S^T, K=32): d = c*32 + g*8 + j, pre-scaled
  s16x8 qf[2];
  {
    const float* qp = Qg + qbase + (size_t)(qb + lm) * HSZ + g * 8;
    const float qs = 0.125f * LOG2E;
#pragma unroll
    for (int c = 0; c < 2; ++c) {
      f32x4 a = *(const f32x4*)(qp + c * 32);
      f32x4 b2 = *(const f32x4*)(qp + c * 32 + 4);
      bf16x8 bv;
#pragma unroll
      for (int j2 = 0; j2 < 4; ++j2) {
        bv[j2] = (__bf16)(a[j2] * qs);
        bv[4 + j2] = (__bf16)(b2[j2] * qs);
      }
      qf[c] = __builtin_bit_cast(s16x8, bv);
    }
  }

  f32x4 oacc[4] = {{0,0,0,0},{0,0,0,0},{0,0,0,0},{0,0,0,0}};
  float m = -1e30f, lsum = 0.0f;

  // non-diagonal range for this half: A = [0, n/2), B = [n/2, n-1)
  const int s0 = half ? (n >> 1) : 0;
  const int s1 = half ? (n - 1) : (n >> 1);
  for (int sub = s0; sub < s1; ++sub) SUBTILE(sub, false)
  if (half) SUBTILE(t, true)   // diagonal subtile, masked

  // ---- merge partials: B publishes, A merges + stores ----
  if (half) {
#pragma unroll
    for (int nb = 0; nb < 4; ++nb)
#pragma unroll
      for (int r = 0; r < 4; ++r) lo[qw][nb * 4 + r][lane] = oacc[nb][r];
    lml[qw][0][lane] = m;
    lml[qw][1][lane] = lsum;
  }
  __syncthreads();
  if (!half) {
    const float mB = lml[qw][0][lane];
    const float lB = lml[qw][1][lane];
    const float mnew = fmaxf(m, mB);
    const float sA = exp2f(m - mnew);
    const float sB = exp2f(mB - mnew);
    float l = lsum * sA + lB * sB;
    l += __shfl_xor(l, 16);
    l += __shfl_xor(l, 32);
    const float inv = 1.0f / l;
    float* op = Og + qbase + (size_t)(qb + lm) * HSZ + g * 4;
#pragma unroll
    for (int nb = 0; nb < 4; ++nb) {
      f32x4 o;
#pragma unroll
      for (int r = 0; r < 4; ++r)
        o[r] = (oacc[nb][r] * sA + lo[qw][nb * 4 + r][lane] * sB) * inv;
      *(f32x4*)(op + nb * 16) = o;
    }
  }
}

// ---- fallback (round-1 kernel) if ws too small ---------------------------
__global__ __launch_bounds__(256) void attn_fwd(
    const float* __restrict__ Qg, const float* __restrict__ Kg,
    const float* __restrict__ Vg, float* __restrict__ Og)
{
  const int tid  = threadIdx.x;
  const int lane = tid & 63;
  const int lm   = lane & 15;
  const int g    = lane >> 4;
  const int w    = tid >> 6;
  const int bh = blockIdx.x;
  const int b  = bh >> 4;
  const int h  = bh & 15;
  const int t  = ((gridDim.y - 1 - blockIdx.y) << 2) | w;
  const int qb = t << 4;
  const size_t base = (size_t)b * SS * HSZ + (size_t)h * DD;
  s16x4 qf[4];
  {
    const float* qp = Qg + base + (size_t)(qb + lm) * HSZ + g * 4;
    const float qs = 0.125f * LOG2E;
#pragma unroll
    for (int c = 0; c < 4; ++c) {
      f32x4 qv = *(const f32x4*)(qp + c * 16);
      bf16x4 bv;
#pragma unroll
      for (int j = 0; j < 4; ++j) bv[j] = (__bf16)(qv[j] * qs);
      qf[c] = __builtin_bit_cast(s16x4, bv);
    }
  }
  f32x4 oacc[4] = {{0,0,0,0},{0,0,0,0},{0,0,0,0},{0,0,0,0}};
  float m = -1e30f, lsum = 0.0f;
  const float* kp = Kg + base + (size_t)lm * HSZ + g * 4;
  const float* vp = Vg + base + (size_t)(g * 4) * HSZ + lm;
  for (int kt = 0; kt <= t; ++kt) {
    const float* kpp = kp + (size_t)(kt << 4) * HSZ;
    f32x4 st = {0, 0, 0, 0};
#pragma unroll
    for (int c = 0; c < 4; ++c) {
      f32x4 kv = *(const f32x4*)(kpp + c * 16);
      bf16x4 bv;
#pragma unroll
      for (int j = 0; j < 4; ++j) bv[j] = (__bf16)kv[j];
      st = __builtin_amdgcn_mfma_f32_16x16x16bf16_1k(
               __builtin_bit_cast(s16x4, bv), qf[c], st, 0, 0, 0);
    }
    if (kt == t) {
#pragma unroll
      for (int r = 0; r < 4; ++r)
        if (g * 4 + r > lm) st[r] = -1e30f;
    }
    float tmax = fmaxf(fmaxf(st[0], st[1]), fmaxf(st[2], st[3]));
    tmax = fmaxf(tmax, __shfl_xor(tmax, 16));
    tmax = fmaxf(tmax, __shfl_xor(tmax, 32));
    const float mnew = fmaxf(m, tmax);
    const float fsc  = exp2f(m - mnew);
    f32x4 p;
#pragma unroll
    for (int r = 0; r < 4; ++r) p[r] = exp2f(st[r] - mnew);
    float tsum = (p[0] + p[1]) + (p[2] + p[3]);
    tsum += __shfl_xor(tsum, 16);
    tsum += __shfl_xor(tsum, 32);
    lsum = lsum * fsc + tsum;
    m = mnew;
#pragma unroll
    for (int nb = 0; nb < 4; ++nb)
#pragma unroll
      for (int r = 0; r < 4; ++r) oacc[nb][r] *= fsc;
    bf16x4 pb;
#pragma unroll
    for (int r = 0; r < 4; ++r) pb[r] = (__bf16)p[r];
    const s16x4 pf = __builtin_bit_cast(s16x4, pb);
    const float* vpp = vp + (size_t)(kt << 4) * HSZ;
#pragma unroll
    for (int nb = 0; nb < 4; ++nb) {
      bf16x4 vv;
#pragma unroll
      for (int j = 0; j < 4; ++j)
        vv[j] = (__bf16)vpp[(size_t)j * HSZ + nb * 16];
      oacc[nb] = __builtin_amdgcn_mfma_f32_16x16x16bf16_1k(
                     __builtin_bit_cast(s16x4, vv), pf, oacc[nb], 0, 0, 0);
    }
  }
  const float inv = 1.0f / lsum;
  float* op = Og + base + (size_t)(qb + lm) * HSZ + g * 4;
#pragma unroll
  for (int nb = 0; nb < 4; ++nb) {
    f32x4 o = oacc[nb];
#pragma unroll
    for (int r = 0; r < 4; ++r) o[r] *= inv;
    *(f32x4*)(op + nb * 16) = o;
  }
}

extern "C" void kernel_launch(void* const* d_in, const int* in_sizes, int n_in,
                              void* d_out, int out_size, void* d_ws, size_t ws_size,
                              hipStream_t stream) {
  const float* q = (const float*)d_in[0];
  const float* k = (const float*)d_in[1];
  const float* v = (const float*)d_in[2];
  float* o = (float*)d_out;
  const size_t elems = (size_t)2 * HH * SS * DD;     // 4,194,304 per tensor
  const size_t need  = 2 * elems * sizeof(short);    // Kf + Vf, 16.8 MB
  if (ws_size >= need) {
    short* Kf = (short*)d_ws;
    short* Vf = Kf + elems;
    prep_k2<<<2048, 256, 0, stream>>>(k, Kf);
    prep_v2<<<4096, 256, 0, stream>>>(v, Vf);
    attn_fwd5<<<dim3(32, 32), 512, 0, stream>>>(q, Kf, Vf, o);
  } else {
    attn_fwd<<<dim3(32, 32), 256, 0, stream>>>(q, k, v, o);
  }
}

// Round 6
// 59.222 us; speedup vs baseline: 1.3284x; 1.3284x over previous
//
#include <hip/hip_runtime.h>

#define LOG2E 1.4426950408889634f

typedef __attribute__((ext_vector_type(4))) float f32x4;
typedef __attribute__((ext_vector_type(4))) short s16x4;
typedef __attribute__((ext_vector_type(8))) short s16x8;
typedef __attribute__((ext_vector_type(4))) __bf16 bf16x4;
typedef __attribute__((ext_vector_type(8))) __bf16 bf16x8;

// B=2 S=2048 H=16 D=64, fp32 in/out.
#define SS 2048
#define HH 16
#define DD 64
#define HSZ (HH * DD)
#define BHSZ (SS * DD)  // 131072 elems per (b,h) plane

// ---- prep 1: K [B,S,H,D] f32 -> Kf fragment-major bf16 -------------------
// Kf[bh][subtile s][c][lane][j]: lane l -> K[key=s*16+(l&15)][d=c*32+(l>>4)*8+j]
__global__ __launch_bounds__(256) void prep_k2(const float* __restrict__ Kg,
                                               short* __restrict__ Kf) {
  const int idx = blockIdx.x * 256 + threadIdx.x;  // 524,288 chunks
  const int l  = idx & 63;
  const int c  = (idx >> 6) & 1;
  const int s  = (idx >> 7) & 127;
  const int bh = idx >> 14;
  const int b = bh >> 4, h = bh & 15;
  const int key = (s << 4) + (l & 15);
  const int d0  = (c << 5) + ((l >> 4) << 3);
  const float* src = Kg + (((size_t)b * SS + key) * HH + h) * DD + d0;
  f32x4 a = *(const f32x4*)(src);
  f32x4 b2 = *(const f32x4*)(src + 4);
  bf16x8 o;
#pragma unroll
  for (int j = 0; j < 4; ++j) {
    o[j] = (__bf16)a[j];
    o[4 + j] = (__bf16)b2[j];
  }
  *(s16x8*)(Kf + (size_t)idx * 8) = __builtin_bit_cast(s16x8, o);
}

// ---- prep 2: V [B,S,H,D] f32 -> Vf fragment-major bf16 -------------------
// Vf[bh][subtile s][nb][lane][j]: lane l -> V[key=s*16+(l>>4)*4+j][d=nb*16+(l&15)]
__global__ __launch_bounds__(256) void prep_v2(const float* __restrict__ Vg,
                                               short* __restrict__ Vf) {
  const int idx = blockIdx.x * 256 + threadIdx.x;  // 1,048,576 chunks
  const int l  = idx & 63;
  const int nb = (idx >> 6) & 3;
  const int s  = (idx >> 8) & 127;
  const int bh = idx >> 15;
  const int b = bh >> 4, h = bh & 15;
  const int d    = (nb << 4) + (l & 15);
  const int key0 = (s << 4) + ((l >> 4) << 2);
  const float* src = Vg + (((size_t)b * SS + key0) * HH + h) * DD + d;
  bf16x4 o;
#pragma unroll
  for (int j = 0; j < 4; ++j) o[j] = (__bf16)src[(size_t)j * HSZ];
  *(s16x4*)(Vf + (size_t)idx * 4) = __builtin_bit_cast(s16x4, o);
}

// ---- main: flash attention, 32 q-rows/wave, split-K, XCD-local bh --------
// Block = 256 threads = 4 waves = 2 q-pairs x 2 key-halves. Each wave owns
// TWO adjacent 16-row q-tiles (t0=2u, t1=2u+1) sharing every K/V fragment
// load (2x reuse vs round 5). Split-K: half A = subtiles [0,na), half B =
// [na,t0) + diag(t0) + diag(t1); merged log-sum-exp via LDS; A stores.
// XCD swizzle: linear block id round-robins XCDs, so bh = (id&7)*4 + low
// bits => each XCD touches only 4 heads = 4MB K/V = its L2 capacity.
// Vote-deferred softmax (THR=8 in log2 -> P <= 256), l lane-local until
// the epilogue.

#define SOFTPV(stv, M, mm, ll, oacc, qtile_pf_mfma)                          \
  {                                                                          \
    if (M) {                                                                 \
      _Pragma("unroll") for (int r = 0; r < 4; ++r)                          \
          if (g * 4 + r > lm) stv[r] = -1e30f;                               \
    }                                                                        \
    float tmax = fmaxf(fmaxf(stv[0], stv[1]), fmaxf(stv[2], stv[3]));        \
    if (!__all(tmax <= mm + 8.0f)) {                                         \
      float tm = fmaxf(tmax, __shfl_xor(tmax, 16));                          \
      tm = fmaxf(tm, __shfl_xor(tm, 32));                                    \
      const float mnew = fmaxf(mm, tm);                                      \
      const float fsc = exp2f(mm - mnew);                                    \
      _Pragma("unroll") for (int nb = 0; nb < 4; ++nb)                       \
          _Pragma("unroll") for (int r = 0; r < 4; ++r) oacc[nb][r] *= fsc;  \
      ll *= fsc;                                                             \
      mm = mnew;                                                             \
    }                                                                        \
    f32x4 p;                                                                 \
    _Pragma("unroll") for (int r = 0; r < 4; ++r) p[r] = exp2f(stv[r] - mm); \
    ll += (p[0] + p[1]) + (p[2] + p[3]);                                     \
    bf16x4 pb;                                                               \
    _Pragma("unroll") for (int r = 0; r < 4; ++r) pb[r] = (__bf16)p[r];      \
    const s16x4 pf = __builtin_bit_cast(s16x4, pb);                          \
    oacc[0] = __builtin_amdgcn_mfma_f32_16x16x16bf16_1k(vv0, pf, oacc[0], 0, 0, 0); \
    oacc[1] = __builtin_amdgcn_mfma_f32_16x16x16bf16_1k(vv1, pf, oacc[1], 0, 0, 0); \
    oacc[2] = __builtin_amdgcn_mfma_f32_16x16x16bf16_1k(vv2, pf, oacc[2], 0, 0, 0); \
    oacc[3] = __builtin_amdgcn_mfma_f32_16x16x16bf16_1k(vv3, pf, oacc[3], 0, 0, 0); \
  }

// DO0/DO1: process tile0/tile1; M0/M1: apply diagonal mask to that tile.
#define SUBTILE2(sub, DO0, M0, DO1, M1)                                      \
  {                                                                          \
    const short* ka = kb2 + ((size_t)(sub) << 10);                           \
    const s16x8 k0 = *(const s16x8*)(ka);                                    \
    const s16x8 k1 = *(const s16x8*)(ka + 512);                              \
    const short* vpp = vb2 + ((size_t)(sub) << 10);                          \
    const s16x4 vv0 = *(const s16x4*)(vpp);                                  \
    const s16x4 vv1 = *(const s16x4*)(vpp + 256);                            \
    const s16x4 vv2 = *(const s16x4*)(vpp + 512);                            \
    const s16x4 vv3 = *(const s16x4*)(vpp + 768);                            \
    if (DO0) {                                                               \
      f32x4 stv = {0, 0, 0, 0};                                              \
      stv = __builtin_amdgcn_mfma_f32_16x16x32_bf16(k0, qf0[0], stv, 0, 0, 0);\
      stv = __builtin_amdgcn_mfma_f32_16x16x32_bf16(k1, qf0[1], stv, 0, 0, 0);\
      SOFTPV(stv, M0, m0, l0, oacc0, 0)                                      \
    }                                                                        \
    if (DO1) {                                                               \
      f32x4 stv = {0, 0, 0, 0};                                              \
      stv = __builtin_amdgcn_mfma_f32_16x16x32_bf16(k0, qf1[0], stv, 0, 0, 0);\
      stv = __builtin_amdgcn_mfma_f32_16x16x32_bf16(k1, qf1[1], stv, 0, 0, 0);\
      SOFTPV(stv, M1, m1, l1, oacc1, 1)                                      \
    }                                                                        \
  }

__global__ __launch_bounds__(256, 4) void attn_fwd6(
    const float* __restrict__ Qg, const short* __restrict__ Kf,
    const short* __restrict__ Vf, float* __restrict__ Og)
{
  __shared__ float lo[2][32][64];   // half-B oacc  [qpair][reg][lane]
  __shared__ float lml[2][4][64];   // half-B m0,l0,m1,l1

  const int tid  = threadIdx.x;
  const int lane = tid & 63;
  const int lm   = lane & 15;
  const int g    = lane >> 4;
  const int w    = tid >> 6;    // 0..3
  const int qw   = w >> 1;      // q-pair slot in block (0..1)
  const int half = w & 1;       // 0 = low keys (+merge), 1 = high keys (+diag)

  // XCD-local mapping: id%8 = XCD (round-robin dispatch heuristic).
  const int id   = blockIdx.x;            // 0..1023
  const int xcd  = id & 7;
  const int slot = id >> 3;               // 0..127
  const int bh   = (xcd << 2) | (slot & 3);
  const int qgrp = slot >> 2;             // 0..31
  const int u    = ((31 - qgrp) << 1) | qw;  // q-pair 0..63, heavy-first
  const int t0   = u << 1, t1 = t0 + 1;

  const size_t qbase = (size_t)(bh >> 4) * SS * HSZ + (size_t)(bh & 15) * DD;
  const short* kb2 = Kf + (size_t)bh * BHSZ + lane * 8;
  const short* vb2 = Vf + (size_t)bh * BHSZ + lane * 4;

  // Q frags for both tiles (B operand of S^T, K=32): d = c*32+g*8+j, scaled
  s16x8 qf0[2], qf1[2];
  {
    const float qs = 0.125f * LOG2E;
#pragma unroll
    for (int x = 0; x < 2; ++x) {
      const float* qp = Qg + qbase + (size_t)(((t0 + x) << 4) + lm) * HSZ + g * 8;
#pragma unroll
      for (int c = 0; c < 2; ++c) {
        f32x4 a = *(const f32x4*)(qp + c * 32);
        f32x4 b2 = *(const f32x4*)(qp + c * 32 + 4);
        bf16x8 bv;
#pragma unroll
        for (int j2 = 0; j2 < 4; ++j2) {
          bv[j2] = (__bf16)(a[j2] * qs);
          bv[4 + j2] = (__bf16)(b2[j2] * qs);
        }
        if (x == 0) qf0[c] = __builtin_bit_cast(s16x8, bv);
        else        qf1[c] = __builtin_bit_cast(s16x8, bv);
      }
    }
  }

  f32x4 oacc0[4] = {{0,0,0,0},{0,0,0,0},{0,0,0,0},{0,0,0,0}};
  f32x4 oacc1[4] = {{0,0,0,0},{0,0,0,0},{0,0,0,0},{0,0,0,0}};
  float m0 = -1e30f, l0 = 0.0f, m1 = -1e30f, l1 = 0.0f;

  const int na = (u == 0) ? 0 : (u + 1);  // A/B split (balanced: u+1 each)

  if (!half) {
    for (int s = 0; s < na; ++s) SUBTILE2(s, 1, 0, 1, 0)
  } else {
    for (int s = na; s < t0; ++s) SUBTILE2(s, 1, 0, 1, 0)
    SUBTILE2(t0, 1, 1, 1, 0)   // diag for tile0, plain for tile1
    SUBTILE2(t1, 0, 0, 1, 1)   // tile1 diag only
  }

  // ---- merge partials: B publishes, A merges + stores both tiles ----
  if (half) {
#pragma unroll
    for (int nb = 0; nb < 4; ++nb)
#pragma unroll
      for (int r = 0; r < 4; ++r) {
        lo[qw][nb * 4 + r][lane] = oacc0[nb][r];
        lo[qw][16 + nb * 4 + r][lane] = oacc1[nb][r];
      }
    lml[qw][0][lane] = m0;
    lml[qw][1][lane] = l0;
    lml[qw][2][lane] = m1;
    lml[qw][3][lane] = l1;
  }
  __syncthreads();
  if (!half) {
#pragma unroll
    for (int x = 0; x < 2; ++x) {
      const float mA = x ? m1 : m0;
      const float lA = x ? l1 : l0;
      const float mB = lml[qw][2 * x][lane];
      const float lB = lml[qw][2 * x + 1][lane];
      const float mnew = fmaxf(mA, mB);
      const float sA = exp2f(mA - mnew);
      const float sB = exp2f(mB - mnew);
      float l = lA * sA + lB * sB;
      l += __shfl_xor(l, 16);
      l += __shfl_xor(l, 32);
      const float inv = 1.0f / l;
      float* op = Og + qbase + (size_t)(((t0 + x) << 4) + lm) * HSZ + g * 4;
#pragma unroll
      for (int nb = 0; nb < 4; ++nb) {
        f32x4 o;
#pragma unroll
        for (int r = 0; r < 4; ++r) {
          const float a = x ? oacc1[nb][r] : oacc0[nb][r];
          o[r] = (a * sA + lo[qw][x * 16 + nb * 4 + r][lane] * sB) * inv;
        }
        *(f32x4*)(op + nb * 16) = o;
      }
    }
  }
}

// ---- fallback (round-1 kernel) if ws too small ---------------------------
__global__ __launch_bounds__(256) void attn_fwd(
    const float* __restrict__ Qg, const float* __restrict__ Kg,
    const float* __restrict__ Vg, float* __restrict__ Og)
{
  const int tid  = threadIdx.x;
  const int lane = tid & 63;
  const int lm   = lane & 15;
  const int g    = lane >> 4;
  const int w    = tid >> 6;
  const int bh = blockIdx.x;
  const int b  = bh >> 4;
  const int h  = bh & 15;
  const int t  = ((gridDim.y - 1 - blockIdx.y) << 2) | w;
  const int qb = t << 4;
  const size_t base = (size_t)b * SS * HSZ + (size_t)h * DD;
  s16x4 qf[4];
  {
    const float* qp = Qg + base + (size_t)(qb + lm) * HSZ + g * 4;
    const float qs = 0.125f * LOG2E;
#pragma unroll
    for (int c = 0; c < 4; ++c) {
      f32x4 qv = *(const f32x4*)(qp + c * 16);
      bf16x4 bv;
#pragma unroll
      for (int j = 0; j < 4; ++j) bv[j] = (__bf16)(qv[j] * qs);
      qf[c] = __builtin_bit_cast(s16x4, bv);
    }
  }
  f32x4 oacc[4] = {{0,0,0,0},{0,0,0,0},{0,0,0,0},{0,0,0,0}};
  float m = -1e30f, lsum = 0.0f;
  const float* kp = Kg + base + (size_t)lm * HSZ + g * 4;
  const float* vp = Vg + base + (size_t)(g * 4) * HSZ + lm;
  for (int kt = 0; kt <= t; ++kt) {
    const float* kpp = kp + (size_t)(kt << 4) * HSZ;
    f32x4 st = {0, 0, 0, 0};
#pragma unroll
    for (int c = 0; c < 4; ++c) {
      f32x4 kv = *(const f32x4*)(kpp + c * 16);
      bf16x4 bv;
#pragma unroll
      for (int j = 0; j < 4; ++j) bv[j] = (__bf16)kv[j];
      st = __builtin_amdgcn_mfma_f32_16x16x16bf16_1k(
               __builtin_bit_cast(s16x4, bv), qf[c], st, 0, 0, 0);
    }
    if (kt == t) {
#pragma unroll
      for (int r = 0; r < 4; ++r)
        if (g * 4 + r > lm) st[r] = -1e30f;
    }
    float tmax = fmaxf(fmaxf(st[0], st[1]), fmaxf(st[2], st[3]));
    tmax = fmaxf(tmax, __shfl_xor(tmax, 16));
    tmax = fmaxf(tmax, __shfl_xor(tmax, 32));
    const float mnew = fmaxf(m, tmax);
    const float fsc  = exp2f(m - mnew);
    f32x4 p;
#pragma unroll
    for (int r = 0; r < 4; ++r) p[r] = exp2f(st[r] - mnew);
    float tsum = (p[0] + p[1]) + (p[2] + p[3]);
    tsum += __shfl_xor(tsum, 16);
    tsum += __shfl_xor(tsum, 32);
    lsum = lsum * fsc + tsum;
    m = mnew;
#pragma unroll
    for (int nb = 0; nb < 4; ++nb)
#pragma unroll
      for (int r = 0; r < 4; ++r) oacc[nb][r] *= fsc;
    bf16x4 pb;
#pragma unroll
    for (int r = 0; r < 4; ++r) pb[r] = (__bf16)p[r];
    const s16x4 pf = __builtin_bit_cast(s16x4, pb);
    const float* vpp = vp + (size_t)(kt << 4) * HSZ;
#pragma unroll
    for (int nb = 0; nb < 4; ++nb) {
      bf16x4 vv;
#pragma unroll
      for (int j = 0; j < 4; ++j)
        vv[j] = (__bf16)vpp[(size_t)j * HSZ + nb * 16];
      oacc[nb] = __builtin_amdgcn_mfma_f32_16x16x16bf16_1k(
                     __builtin_bit_cast(s16x4, vv), pf, oacc[nb], 0, 0, 0);
    }
  }
  const float inv = 1.0f / lsum;
  float* op = Og + base + (size_t)(qb + lm) * HSZ + g * 4;
#pragma unroll
  for (int nb = 0; nb < 4; ++nb) {
    f32x4 o = oacc[nb];
#pragma unroll
    for (int r = 0; r < 4; ++r) o[r] *= inv;
    *(f32x4*)(op + nb * 16) = o;
  }
}

extern "C" void kernel_launch(void* const* d_in, const int* in_sizes, int n_in,
                              void* d_out, int out_size, void* d_ws, size_t ws_size,
                              hipStream_t stream) {
  const float* q = (const float*)d_in[0];
  const float* k = (const float*)d_in[1];
  const float* v = (const float*)d_in[2];
  float* o = (float*)d_out;
  const size_t elems = (size_t)2 * HH * SS * DD;     // 4,194,304 per tensor
  const size_t need  = 2 * elems * sizeof(short);    // Kf + Vf, 16.8 MB
  if (ws_size >= need) {
    short* Kf = (short*)d_ws;
    short* Vf = Kf + elems;
    prep_k2<<<2048, 256, 0, stream>>>(k, Kf);
    prep_v2<<<4096, 256, 0, stream>>>(v, Vf);
    attn_fwd6<<<1024, 256, 0, stream>>>(q, Kf, Vf, o);
  } else {
    attn_fwd<<<dim3(32, 32), 256, 0, stream>>>(q, k, v, o);
  }
}